// Round 2
// baseline (569.390 us; speedup 1.0000x reference)
//
#include <hip/hip_runtime.h>
#include <stdint.h>

#define NN 4096
#define NE 65536
#define LEAKY 0.01f
#define BN_EPS 1e-5f

typedef float f32x4 __attribute__((ext_vector_type(4)));
typedef __bf16 bf16x8 __attribute__((ext_vector_type(8)));

static __device__ __forceinline__ unsigned short f2bf(float v) {
  unsigned int u = __float_as_uint(v);
  u += 0x7fff + ((u >> 16) & 1);   // RNE; inputs are finite
  return (unsigned short)(u >> 16);
}

typedef __attribute__((address_space(1))) void gvoid;
typedef __attribute__((address_space(3))) void lvoid;

// async global->LDS, 16B per lane. LDS dest must be wave-uniform-base + lane*16,
// which our flat tile mapping guarantees (m97 pattern).
static __device__ __forceinline__ void async16(const void* g, void* l) {
  __builtin_amdgcn_global_load_lds((gvoid*)(uintptr_t)g,
                                   (lvoid*)(uint32_t)(uintptr_t)l, 16, 0, 0);
}

// ---------------- pack / convert kernels ----------------

// x_in [4096,8500] f32 -> bf16 [4096,8512] (K padded with zeros)
__global__ void pack_x1(const float* __restrict__ x, unsigned short* __restrict__ out) {
  int idx = blockIdx.x * 256 + threadIdx.x;          // exact grid: 4096*8512/256
  int row = idx / 8512;
  int k = idx - row * 8512;
  float v = (k < 8500) ? x[(size_t)row * 8500 + k] : 0.f;
  out[idx] = f2bf(v);
}

// Wcat bf16 [Np, Kp]: rows [0,Fout)=Wl, [Fout,2Fout)=Wr, rest 0; cols >= Fin are 0.
__global__ void pack_w(const float* __restrict__ Wl, const float* __restrict__ Wr,
                       unsigned short* __restrict__ dst, int Fout, int Fin, int Kp, int total) {
  int idx = blockIdx.x * 256 + threadIdx.x;
  if (idx >= total) return;
  int row = idx / Kp;
  int k = idx - row * Kp;
  float v = 0.f;
  if (k < Fin) {
    if (row < Fout)            v = Wl[(size_t)row * Fin + k];
    else if (row < 2 * Fout)   v = Wr[(size_t)(row - Fout) * Fin + k];
  }
  dst[idx] = f2bf(v);
}

// ---------------- CSR build (edge_index is int32 per harness contract) -------

__global__ void count_deg(const int* __restrict__ dst_idx, int* __restrict__ deg) {
  int e = blockIdx.x * 256 + threadIdx.x;
  if (e < NE) atomicAdd(&deg[dst_idx[e]], 1);
}

__global__ __launch_bounds__(1024) void scan_deg(const int* __restrict__ deg,
                                                 int* __restrict__ off) {
  __shared__ int s[NN];
  int t = threadIdx.x;
  for (int i = t; i < NN; i += 1024) s[i] = deg[i];
  __syncthreads();
  for (int step = 1; step < NN; step <<= 1) {
    int v[4];
#pragma unroll
    for (int j = 0; j < 4; ++j) {
      int i = t + j * 1024;
      v[j] = (i >= step) ? s[i - step] : 0;
    }
    __syncthreads();
#pragma unroll
    for (int j = 0; j < 4; ++j) s[t + j * 1024] += v[j];
    __syncthreads();
  }
  for (int i = t; i < NN; i += 1024) off[i] = (i == 0) ? 0 : s[i - 1];
}

__global__ void scatter_edges(const int* __restrict__ src_idx,
                              const int* __restrict__ dst_idx,
                              const int* __restrict__ off, int* __restrict__ cursor,
                              int* __restrict__ eix) {
  int e = blockIdx.x * 256 + threadIdx.x;
  if (e < NE) {
    int d = dst_idx[e];
    int pos = atomicAdd(&cursor[d], 1);
    eix[off[d] + pos] = src_idx[e];
  }
}

// ---------------- bf16 MFMA GEMM: C[M,N] = A[M,K] @ B[N,K]^T ----------------
// 128x128 tile, BK=64, 256 threads (2x2 waves of 64x64). Optional K-split over
// gridDim.z with atomicAdd epilogue (C must be pre-zeroed when gridDim.z>1).
__global__ __launch_bounds__(256) void gemm_bt(const unsigned short* __restrict__ A,
                                               const unsigned short* __restrict__ B,
                                               float* __restrict__ C, int N, int K) {
  __shared__ unsigned short smem[2 * 128 * 64];
  unsigned short* As = smem;
  unsigned short* Bs = smem + 128 * 64;

  const int t = threadIdx.x;
  const int bm = blockIdx.x, bn = blockIdx.y;
  const int lane = t & 63;
  const int wave = t >> 6;
  const int wm = (wave & 1) * 64, wn = (wave >> 1) * 64;
  const int l16 = lane & 15, quad = lane >> 4;

  const int ksteps = K >> 6;
  const int gz = (int)gridDim.z;
  const int per = (ksteps + gz - 1) / gz;
  const int k0 = (int)blockIdx.z * per;
  int k1 = k0 + per; if (k1 > ksteps) k1 = ksteps;

  f32x4 zero = {0.f, 0.f, 0.f, 0.f};
  f32x4 acc[4][4];
#pragma unroll
  for (int i = 0; i < 4; ++i)
#pragma unroll
    for (int j = 0; j < 4; ++j) acc[i][j] = zero;

  const int srow = t >> 3;          // 0..31
  const int scol = (t & 7) * 8;     // bf16 col, 16B chunks
  const unsigned short* Abase = A + (size_t)(bm * 128) * K + scol;
  const unsigned short* Bbase = B + (size_t)(bn * 128) * K + scol;

  for (int kt = k0; kt < k1; ++kt) {
    const unsigned short* Ag = Abase + kt * 64;
    const unsigned short* Bg = Bbase + kt * 64;
#pragma unroll
    for (int p = 0; p < 4; ++p) {
      int row = p * 32 + srow;
      async16(Ag + (size_t)row * K, &As[row * 64 + scol]);
    }
#pragma unroll
    for (int p = 0; p < 4; ++p) {
      int row = p * 32 + srow;
      async16(Bg + (size_t)row * K, &Bs[row * 64 + scol]);
    }
    __syncthreads();   // compiler emits vmcnt(0) drain before s_barrier
#pragma unroll
    for (int kh = 0; kh < 2; ++kh) {
      bf16x8 af[4], bfr[4];
#pragma unroll
      for (int i = 0; i < 4; ++i)
        af[i] = *(const bf16x8*)&As[(wm + i * 16 + l16) * 64 + kh * 32 + quad * 8];
#pragma unroll
      for (int j = 0; j < 4; ++j)
        bfr[j] = *(const bf16x8*)&Bs[(wn + j * 16 + l16) * 64 + kh * 32 + quad * 8];
#pragma unroll
      for (int i = 0; i < 4; ++i)
#pragma unroll
        for (int j = 0; j < 4; ++j)
          acc[i][j] = __builtin_amdgcn_mfma_f32_16x16x32_bf16(af[i], bfr[j], acc[i][j], 0, 0, 0);
    }
    __syncthreads();
  }

  // C/D layout: row = quad*4 + reg, col = lane&15 (m89/m91-verified)
  const bool use_atomic = (gridDim.z > 1);
#pragma unroll
  for (int i = 0; i < 4; ++i) {
    int rbase = bm * 128 + wm + i * 16 + quad * 4;
#pragma unroll
    for (int j = 0; j < 4; ++j) {
      int col = bn * 128 + wn + j * 16 + l16;
      float* cp = C + (size_t)rbase * N + col;
#pragma unroll
      for (int r = 0; r < 4; ++r) {
        if (use_atomic) atomicAdd(cp + (size_t)r * N, acc[i][j][r]);
        else            cp[(size_t)r * N] = acc[i][j][r];
      }
    }
  }
}

// ---------------- fused mean-aggregate + root + bias + leaky ----------------
// y [4096, ldy]: cols [0,F) = x@Wl^T, cols [F,2F) = x@Wr^T.
// z[i,f] = leaky( agg_f/max(deg,1) + y[i,F+f] + b[f] )
__global__ void sage_agg(const float* __restrict__ y, const int* __restrict__ off,
                         const int* __restrict__ deg, const int* __restrict__ eix,
                         const float* __restrict__ bias, float* __restrict__ z,
                         int F, int ldy) {
  int i = blockIdx.x;
  int f = blockIdx.y * 64 + threadIdx.x;
  if (f >= F) return;
  int start = off[i], d = deg[i];
  float s = 0.f;
  for (int e = 0; e < d; ++e) {
    int src = eix[start + e];
    s += y[(size_t)src * ldy + f];
  }
  int dm = d > 1 ? d : 1;
  float v = s / (float)dm + y[(size_t)i * ldy + F + f] + bias[f];
  z[(size_t)i * F + f] = (v >= 0.f) ? v : LEAKY * v;
}

// ---------------- batchnorm ----------------

__global__ void bn_stats(const float* __restrict__ z, float* __restrict__ mrs, int F) {
  int f = blockIdx.x;
  int t = threadIdx.x;
  float s = 0.f, s2 = 0.f;
  for (int i = t; i < NN; i += 256) {
    float v = z[(size_t)i * F + f];
    s += v; s2 += v * v;
  }
  __shared__ float rs[256], rs2[256];
  rs[t] = s; rs2[t] = s2;
  __syncthreads();
  for (int o = 128; o > 0; o >>= 1) {
    if (t < o) { rs[t] += rs[t + o]; rs2[t] += rs2[t + o]; }
    __syncthreads();
  }
  if (t == 0) {
    float m = rs[0] * (1.f / NN);
    float var = rs2[0] * (1.f / NN) - m * m;
    mrs[f] = m;
    mrs[F + f] = 1.f / sqrtf(var + BN_EPS);
  }
}

// normalize -> next layer's bf16 input, K-padded with zeros
__global__ void bn_norm_bf16(const float* __restrict__ z, const float* __restrict__ mrs,
                             unsigned short* __restrict__ xout, int F, int Kp, int total) {
  int idx = blockIdx.x * 256 + threadIdx.x;
  if (idx >= total) return;
  int row = idx / Kp;
  int k = idx - row * Kp;
  float v = 0.f;
  if (k < F) v = (z[(size_t)row * F + k] - mrs[k]) * mrs[F + k];
  xout[idx] = f2bf(v);
}

__global__ void bn_norm_f32(const float* __restrict__ z, const float* __restrict__ mrs,
                            float* __restrict__ xout, int F, int total) {
  int idx = blockIdx.x * 256 + threadIdx.x;
  if (idx >= total) return;
  int row = idx / F;
  int k = idx - row * F;
  xout[idx] = (z[(size_t)row * F + k] - mrs[k]) * mrs[F + k];
}

// ---------------- pool (sum of 256-node blocks) + 3 FC layers ----------------
__global__ void pool_fc(const float* __restrict__ x,  // [4096, 50]
                        const float* __restrict__ Wf1, const float* __restrict__ bf1,
                        const float* __restrict__ Wf2, const float* __restrict__ bf2,
                        const float* __restrict__ Wf3, const float* __restrict__ bf3,
                        float* __restrict__ out) {
  __shared__ float pool[50];
  __shared__ float h1[32], h2[16];
  int b = blockIdx.x, t = threadIdx.x;  // 64 threads
  if (t < 50) {
    float s = 0.f;
    for (int r = 0; r < 256; ++r) s += x[(size_t)(b * 256 + r) * 50 + t];
    pool[t] = s;
  }
  __syncthreads();
  if (t < 32) {
    float s = bf1[t];
    for (int f = 0; f < 50; ++f) s += pool[f] * Wf1[t * 50 + f];
    h1[t] = s;
  }
  __syncthreads();
  if (t < 16) {
    float s = bf2[t];
    for (int f = 0; f < 32; ++f) s += h1[f] * Wf2[t * 32 + f];
    h2[t] = s;
  }
  __syncthreads();
  if (t == 0) {
    float s = bf3[0];
    for (int f = 0; f < 16; ++f) s += h2[f] * Wf3[f];
    out[b] = s;
  }
}

// ---------------- host ----------------

extern "C" void kernel_launch(void* const* d_in, const int* in_sizes, int n_in,
                              void* d_out, int out_size, void* d_ws, size_t ws_size,
                              hipStream_t stream) {
  const float* x_in = (const float*)d_in[0];
  const int* ei = (const int*)d_in[1];      // int32 per harness contract (int64 in ref)
  const float* W1l = (const float*)d_in[2];
  const float* b1  = (const float*)d_in[3];
  const float* W1r = (const float*)d_in[4];
  const float* W2l = (const float*)d_in[5];
  const float* b2  = (const float*)d_in[6];
  const float* W2r = (const float*)d_in[7];
  const float* W3l = (const float*)d_in[8];
  const float* b3  = (const float*)d_in[9];
  const float* W3r = (const float*)d_in[10];
  const float* W4l = (const float*)d_in[11];
  const float* b4  = (const float*)d_in[12];
  const float* W4r = (const float*)d_in[13];
  const float* Wf1 = (const float*)d_in[14];
  const float* bf1 = (const float*)d_in[15];
  const float* Wf2 = (const float*)d_in[16];
  const float* bf2 = (const float*)d_in[17];
  const float* Wf3 = (const float*)d_in[18];
  const float* bf3 = (const float*)d_in[19];
  float* out = (float*)d_out;
  (void)in_sizes; (void)n_in; (void)out_size;

  char* ws = (char*)d_ws;
  size_t off = 0;
  auto alloc = [&](size_t bytes) -> void* {
    void* p = ws + off;
    off = (off + bytes + 255) & ~(size_t)255;
    return p;
  };
  unsigned short* xbf = (unsigned short*)alloc((size_t)NN * 8512 * 2);
  unsigned short* wb1 = (unsigned short*)alloc((size_t)640 * 8512 * 2);
  unsigned short* wb2 = (unsigned short*)alloc((size_t)384 * 320 * 2);
  unsigned short* wb3 = (unsigned short*)alloc((size_t)256 * 192 * 2);
  unsigned short* wb4 = (unsigned short*)alloc((size_t)128 * 128 * 2);
  float* y    = (float*)alloc((size_t)NN * 640 * 4);
  float* z    = (float*)alloc((size_t)NN * 320 * 4);
  float* z4   = (float*)alloc((size_t)NN * 50 * 4);
  float* mrs  = (float*)alloc(2 * 320 * 4);
  int* deg    = (int*)alloc(NN * 4);
  int* cursor = (int*)alloc(NN * 4);   // contiguous after deg (both 16KB, 256-aligned)
  int* offb   = (int*)alloc(NN * 4);
  int* eix    = (int*)alloc(NE * 4);
  if (ws_size < off) return;  // workspace too small; nothing sane to do

  // zero: deg + cursor (one contiguous memset), and y (atomic K-split epilogue)
  hipMemsetAsync(deg, 0, 2 * NN * 4, stream);
  hipMemsetAsync(y, 0, (size_t)NN * 640 * 4, stream);

  // packs + CSR
  pack_x1<<<dim3((NN * 8512) / 256), dim3(256), 0, stream>>>(x_in, xbf);
  pack_w<<<dim3((640 * 8512) / 256), dim3(256), 0, stream>>>(W1l, W1r, wb1, 320, 8500, 8512, 640 * 8512);
  pack_w<<<dim3((384 * 320 + 255) / 256), dim3(256), 0, stream>>>(W2l, W2r, wb2, 180, 320, 320, 384 * 320);
  pack_w<<<dim3((256 * 192 + 255) / 256), dim3(256), 0, stream>>>(W3l, W3r, wb3, 90, 180, 192, 256 * 192);
  pack_w<<<dim3((128 * 128 + 255) / 256), dim3(256), 0, stream>>>(W4l, W4r, wb4, 50, 90, 128, 128 * 128);
  count_deg<<<dim3(NE / 256), dim3(256), 0, stream>>>(ei + NE, deg);
  scan_deg<<<dim3(1), dim3(1024), 0, stream>>>(deg, offb);
  scatter_edges<<<dim3(NE / 256), dim3(256), 0, stream>>>(ei, ei + NE, offb, cursor, eix);

  // ---- layer 1: K=8512, N=640, K-split x4 ----
  gemm_bt<<<dim3(32, 5, 4), dim3(256), 0, stream>>>(xbf, wb1, y, 640, 8512);
  sage_agg<<<dim3(NN, 5), dim3(64), 0, stream>>>(y, offb, deg, eix, b1, z, 320, 640);
  bn_stats<<<dim3(320), dim3(256), 0, stream>>>(z, mrs, 320);
  bn_norm_bf16<<<dim3((NN * 320) / 256), dim3(256), 0, stream>>>(z, mrs, xbf, 320, 320, NN * 320);

  // ---- layer 2: K=320, N=384 ----
  gemm_bt<<<dim3(32, 3, 1), dim3(256), 0, stream>>>(xbf, wb2, y, 384, 320);
  sage_agg<<<dim3(NN, 3), dim3(64), 0, stream>>>(y, offb, deg, eix, b2, z, 180, 384);
  bn_stats<<<dim3(180), dim3(256), 0, stream>>>(z, mrs, 180);
  bn_norm_bf16<<<dim3((NN * 192) / 256), dim3(256), 0, stream>>>(z, mrs, xbf, 180, 192, NN * 192);

  // ---- layer 3: K=192, N=256 ----
  gemm_bt<<<dim3(32, 2, 1), dim3(256), 0, stream>>>(xbf, wb3, y, 256, 192);
  sage_agg<<<dim3(NN, 2), dim3(64), 0, stream>>>(y, offb, deg, eix, b3, z, 90, 256);
  bn_stats<<<dim3(90), dim3(256), 0, stream>>>(z, mrs, 90);
  bn_norm_bf16<<<dim3((NN * 128) / 256), dim3(256), 0, stream>>>(z, mrs, xbf, 90, 128, NN * 128);

  // ---- layer 4: K=128, N=128 ----
  gemm_bt<<<dim3(32, 1, 1), dim3(256), 0, stream>>>(xbf, wb4, y, 128, 128);
  sage_agg<<<dim3(NN, 1), dim3(64), 0, stream>>>(y, offb, deg, eix, b4, z, 50, 128);
  bn_stats<<<dim3(50), dim3(256), 0, stream>>>(z, mrs, 50);
  bn_norm_f32<<<dim3((NN * 50) / 256), dim3(256), 0, stream>>>(z, mrs, z4, 50, NN * 50);

  // ---- pool + FC ----
  pool_fc<<<dim3(16), dim3(64), 0, stream>>>(z4, Wf1, bf1, Wf2, bf2, Wf3, bf3, out);
}

// Round 3
// 559.545 us; speedup vs baseline: 1.0176x; 1.0176x over previous
//
#include <hip/hip_runtime.h>
#include <stdint.h>

#define NN 4096
#define NE 65536
#define LEAKY 0.01f
#define BN_EPS 1e-5f

typedef float f32x4 __attribute__((ext_vector_type(4)));
typedef __bf16 bf16x8 __attribute__((ext_vector_type(8)));
typedef unsigned short u16x8 __attribute__((ext_vector_type(8)));

static __device__ __forceinline__ unsigned short f2bf(float v) {
  unsigned int u = __float_as_uint(v);
  u += 0x7fff + ((u >> 16) & 1);   // RNE; inputs are finite
  return (unsigned short)(u >> 16);
}

typedef __attribute__((address_space(1))) void gvoid;
typedef __attribute__((address_space(3))) void lvoid;

static __device__ __forceinline__ void async16(const void* g, void* l) {
  __builtin_amdgcn_global_load_lds((gvoid*)(uintptr_t)g,
                                   (lvoid*)(uint32_t)(uintptr_t)l, 16, 0, 0);
}

// ======================= fused setup: packs + degree count =================
// bf16 GEMM-input layout: within each 64-col K-group, row r's 16B block b is
// stored at block (b + r) & 7.  The GEMM unrotates at ds_read time; this
// spreads a quad's 16 lanes over all 8 bank-quads (2-way = free) instead of
// 16-way conflicts on one bank-quad.

static __device__ __forceinline__ void pack_w_seg(int lblk, const float* __restrict__ Wl,
                                                  const float* __restrict__ Wr,
                                                  unsigned short* __restrict__ dst,
                                                  int Fout, int Fin, int Kp, int Np) {
  int nb = Kp >> 3;
  int idx = lblk * 256 + threadIdx.x;
  if (idx >= Np * nb) return;
  int row = idx / nb, kb = idx - row * nb;
  int g = kb >> 3, b = kb & 7;
  int dkb = (g << 3) | ((b + row) & 7);
  const float* src = nullptr;
  if (row < Fout)          src = Wl + (size_t)row * Fin;
  else if (row < 2 * Fout) src = Wr + (size_t)(row - Fout) * Fin;
  u16x8 st;
#pragma unroll
  for (int o = 0; o < 8; ++o) {
    int k = kb * 8 + o;
    float v = (src && k < Fin) ? src[k] : 0.f;
    st[o] = f2bf(v);
  }
  *(u16x8*)&dst[(size_t)row * Kp + dkb * 8] = st;
}

#define PX_BLK   17024   // 4096*1064/256
#define PW1_BLK   2660   // 640*1064/256
#define PW2_BLK     60   // ceil(384*40/256)
#define PW3_BLK     24   // ceil(256*24/256)
#define PW4_BLK      8   // ceil(128*16/256)
#define CD_BLK     256   // 65536/256
#define SETUP_BLK (PX_BLK + PW1_BLK + PW2_BLK + PW3_BLK + PW4_BLK + CD_BLK)

__global__ __launch_bounds__(256) void setup_all(
    const float* __restrict__ x, const int* __restrict__ dsti,
    const float* __restrict__ W1l, const float* __restrict__ W1r,
    const float* __restrict__ W2l, const float* __restrict__ W2r,
    const float* __restrict__ W3l, const float* __restrict__ W3r,
    const float* __restrict__ W4l, const float* __restrict__ W4r,
    unsigned short* __restrict__ xbf, unsigned short* __restrict__ wb1,
    unsigned short* __restrict__ wb2, unsigned short* __restrict__ wb3,
    unsigned short* __restrict__ wb4, int* __restrict__ deg) {
  int blk = blockIdx.x;
  if (blk < PX_BLK) {
    // x_in [4096,8500] f32 -> bf16 [4096,8512], rotated blocks
    int idx = blk * 256 + threadIdx.x;
    int row = idx / 1064, kb = idx - row * 1064;
    int g = kb >> 3, b = kb & 7;
    int dkb = (g << 3) | ((b + row) & 7);
    const float* src = x + (size_t)row * 8500 + kb * 8;
    float v[8];
    if (kb < 1062) {
      f32x4 a = *(const f32x4*)src;
      f32x4 c = *(const f32x4*)(src + 4);
#pragma unroll
      for (int o = 0; o < 4; ++o) { v[o] = a[o]; v[o + 4] = c[o]; }
    } else {
#pragma unroll
      for (int o = 0; o < 8; ++o) {
        int k = kb * 8 + o;
        v[o] = (k < 8500) ? x[(size_t)row * 8500 + k] : 0.f;
      }
    }
    u16x8 st;
#pragma unroll
    for (int o = 0; o < 8; ++o) st[o] = f2bf(v[o]);
    *(u16x8*)&xbf[(size_t)row * 8512 + dkb * 8] = st;
  } else if (blk < PX_BLK + PW1_BLK) {
    pack_w_seg(blk - PX_BLK, W1l, W1r, wb1, 320, 8500, 8512, 640);
  } else if (blk < PX_BLK + PW1_BLK + PW2_BLK) {
    pack_w_seg(blk - PX_BLK - PW1_BLK, W2l, W2r, wb2, 180, 320, 320, 384);
  } else if (blk < PX_BLK + PW1_BLK + PW2_BLK + PW3_BLK) {
    pack_w_seg(blk - PX_BLK - PW1_BLK - PW2_BLK, W3l, W3r, wb3, 90, 180, 192, 256);
  } else if (blk < PX_BLK + PW1_BLK + PW2_BLK + PW3_BLK + PW4_BLK) {
    pack_w_seg(blk - PX_BLK - PW1_BLK - PW2_BLK - PW3_BLK, W4l, W4r, wb4, 50, 90, 128, 128);
  } else {
    int e = (blk - (SETUP_BLK - CD_BLK)) * 256 + threadIdx.x;
    atomicAdd(&deg[dsti[e]], 1);
  }
}

// ---------------- CSR scan + scatter ----------------

__global__ __launch_bounds__(1024) void scan_deg(const int* __restrict__ deg,
                                                 int* __restrict__ off) {
  __shared__ int s[NN];
  int t = threadIdx.x;
  for (int i = t; i < NN; i += 1024) s[i] = deg[i];
  __syncthreads();
  for (int step = 1; step < NN; step <<= 1) {
    int v[4];
#pragma unroll
    for (int j = 0; j < 4; ++j) {
      int i = t + j * 1024;
      v[j] = (i >= step) ? s[i - step] : 0;
    }
    __syncthreads();
#pragma unroll
    for (int j = 0; j < 4; ++j) s[t + j * 1024] += v[j];
    __syncthreads();
  }
  for (int i = t; i < NN; i += 1024) off[i] = (i == 0) ? 0 : s[i - 1];
}

__global__ void scatter_edges(const int* __restrict__ src_idx,
                              const int* __restrict__ dst_idx,
                              const int* __restrict__ off, int* __restrict__ cursor,
                              int* __restrict__ eix) {
  int e = blockIdx.x * 256 + threadIdx.x;
  if (e < NE) {
    int d = dst_idx[e];
    int pos = atomicAdd(&cursor[d], 1);
    eix[off[d] + pos] = src_idx[e];
  }
}

// ---------------- bf16 MFMA GEMM: C[M,N] = A[M,K] @ B[N,K]^T ----------------
// 128x128 tile, BK=64, 256 threads.  Inputs use the rotated-block layout; the
// fragment read unrotates: LDS block = (gb + row) & 7 where gb = kh*4+quad.
__global__ __launch_bounds__(256) void gemm_bt(const unsigned short* __restrict__ A,
                                               const unsigned short* __restrict__ B,
                                               float* __restrict__ C, int N, int K) {
  __shared__ unsigned short smem[2 * 128 * 64];
  unsigned short* As = smem;
  unsigned short* Bs = smem + 128 * 64;

  const int t = threadIdx.x;
  const int bm = blockIdx.x, bn = blockIdx.y;
  const int lane = t & 63;
  const int wave = t >> 6;
  const int wm = (wave & 1) * 64, wn = (wave >> 1) * 64;
  const int l16 = lane & 15, quad = lane >> 4;

  const int ksteps = K >> 6;
  const int gz = (int)gridDim.z;
  const int per = (ksteps + gz - 1) / gz;
  const int k0 = (int)blockIdx.z * per;
  int k1 = k0 + per; if (k1 > ksteps) k1 = ksteps;

  f32x4 zero = {0.f, 0.f, 0.f, 0.f};
  f32x4 acc[4][4];
#pragma unroll
  for (int i = 0; i < 4; ++i)
#pragma unroll
    for (int j = 0; j < 4; ++j) acc[i][j] = zero;

  const int srow = t >> 3;          // 0..31
  const int scol = (t & 7) * 8;     // bf16 col, 16B chunks
  const unsigned short* Abase = A + (size_t)(bm * 128) * K + scol;
  const unsigned short* Bbase = B + (size_t)(bn * 128) * K + scol;

  for (int kt = k0; kt < k1; ++kt) {
    const unsigned short* Ag = Abase + kt * 64;
    const unsigned short* Bg = Bbase + kt * 64;
#pragma unroll
    for (int p = 0; p < 4; ++p) {
      int row = p * 32 + srow;
      async16(Ag + (size_t)row * K, &As[row * 64 + scol]);
    }
#pragma unroll
    for (int p = 0; p < 4; ++p) {
      int row = p * 32 + srow;
      async16(Bg + (size_t)row * K, &Bs[row * 64 + scol]);
    }
    __syncthreads();
#pragma unroll
    for (int kh = 0; kh < 2; ++kh) {
      const int s8 = ((kh * 4 + quad + l16) & 7) * 8;   // unrotate
      bf16x8 af[4], bfr[4];
#pragma unroll
      for (int i = 0; i < 4; ++i)
        af[i] = *(const bf16x8*)&As[(wm + i * 16 + l16) * 64 + s8];
#pragma unroll
      for (int j = 0; j < 4; ++j)
        bfr[j] = *(const bf16x8*)&Bs[(wn + j * 16 + l16) * 64 + s8];
#pragma unroll
      for (int i = 0; i < 4; ++i)
#pragma unroll
        for (int j = 0; j < 4; ++j)
          acc[i][j] = __builtin_amdgcn_mfma_f32_16x16x32_bf16(af[i], bfr[j], acc[i][j], 0, 0, 0);
    }
    __syncthreads();
  }

  // C/D layout: row = quad*4 + reg, col = lane&15
  const bool use_atomic = (gridDim.z > 1);
#pragma unroll
  for (int i = 0; i < 4; ++i) {
    int rbase = bm * 128 + wm + i * 16 + quad * 4;
#pragma unroll
    for (int j = 0; j < 4; ++j) {
      int col = bn * 128 + wn + j * 16 + l16;
      float* cp = C + (size_t)rbase * N + col;
#pragma unroll
      for (int r = 0; r < 4; ++r) {
        if (use_atomic) atomicAdd(cp + (size_t)r * N, acc[i][j][r]);
        else            cp[(size_t)r * N] = acc[i][j][r];
      }
    }
  }
}

// ---------------- fused mean-aggregate + root + bias + leaky ----------------
__global__ void sage_agg(const float* __restrict__ y, const int* __restrict__ off,
                         const int* __restrict__ deg, const int* __restrict__ eix,
                         const float* __restrict__ bias, float* __restrict__ z,
                         int F, int ldy) {
  int i = blockIdx.x;
  int f = blockIdx.y * 64 + threadIdx.x;
  if (f >= F) return;
  int start = off[i], d = deg[i];
  float s = 0.f;
  for (int e = 0; e < d; ++e) {
    int src = eix[start + e];
    s += y[(size_t)src * ldy + f];
  }
  int dm = d > 1 ? d : 1;
  float v = s / (float)dm + y[(size_t)i * ldy + F + f] + bias[f];
  z[(size_t)i * F + f] = (v >= 0.f) ? v : LEAKY * v;
}

// ---------------- batchnorm: row-major partial sums + fused finalize --------

__global__ __launch_bounds__(256) void bn_part(const float* __restrict__ z,
                                               float* __restrict__ sums, int F) {
  int tx = threadIdx.x, ty = threadIdx.y;      // block (64,4)
  int f = blockIdx.x * 64 + tx;
  float s = 0.f, s2 = 0.f;
  if (f < F) {
    int r0 = blockIdx.y * 512 + ty * 128;
    for (int j = 0; j < 128; ++j) {
      float v = z[(size_t)(r0 + j) * F + f];
      s += v; s2 += v * v;
    }
  }
  __shared__ float ls[4][64], ls2[4][64];
  ls[ty][tx] = s; ls2[ty][tx] = s2;
  __syncthreads();
  if (ty == 0 && f < F) {
    float S  = ls[0][tx] + ls[1][tx] + ls[2][tx] + ls[3][tx];
    float S2 = ls2[0][tx] + ls2[1][tx] + ls2[2][tx] + ls2[3][tx];
    atomicAdd(&sums[f], S);
    atomicAdd(&sums[F + f], S2);
  }
}

// normalize -> next layer's rotated bf16 input (finalizes BN from sums)
__global__ void bn_norm8(const float* __restrict__ z, const float* __restrict__ sums,
                         unsigned short* __restrict__ xout, int F, int Kp) {
  int nb = Kp >> 3;
  int idx = blockIdx.x * 256 + threadIdx.x;    // exact grid
  int row = idx / nb, kb = idx - row * nb;
  int g = kb >> 3, b = kb & 7;
  int dkb = (g << 3) | ((b + row) & 7);
  u16x8 st;
#pragma unroll
  for (int o = 0; o < 8; ++o) {
    int k = kb * 8 + o;
    float v = 0.f;
    if (k < F) {
      float m  = sums[k] * (1.f / NN);
      float var = sums[F + k] * (1.f / NN) - m * m;
      float rs = rsqrtf(var + BN_EPS);
      v = (z[(size_t)row * F + k] - m) * rs;
    }
    st[o] = f2bf(v);
  }
  *(u16x8*)&xout[(size_t)row * Kp + dkb * 8] = st;
}

// ---------------- pool (BN folded in) + 3 FC layers ----------------
__global__ void pool_fc(const float* __restrict__ z,  // [4096, 50] pre-BN
                        const float* __restrict__ sums,
                        const float* __restrict__ Wf1, const float* __restrict__ bf1,
                        const float* __restrict__ Wf2, const float* __restrict__ bf2,
                        const float* __restrict__ Wf3, const float* __restrict__ bf3,
                        float* __restrict__ out) {
  __shared__ float pool[50];
  __shared__ float h1[32], h2[16];
  int b = blockIdx.x, t = threadIdx.x;  // 64 threads
  if (t < 50) {
    float s = 0.f;
    for (int r = 0; r < 256; ++r) s += z[(size_t)(b * 256 + r) * 50 + t];
    float m  = sums[t] * (1.f / NN);
    float var = sums[50 + t] * (1.f / NN) - m * m;
    float rs = rsqrtf(var + BN_EPS);
    pool[t] = (s - 256.f * m) * rs;   // sum of normalized = (sum - n*m)*rs
  }
  __syncthreads();
  if (t < 32) {
    float s = bf1[t];
    for (int f = 0; f < 50; ++f) s += pool[f] * Wf1[t * 50 + f];
    h1[t] = s;
  }
  __syncthreads();
  if (t < 16) {
    float s = bf2[t];
    for (int f = 0; f < 32; ++f) s += h1[f] * Wf2[t * 32 + f];
    h2[t] = s;
  }
  __syncthreads();
  if (t == 0) {
    float s = bf3[0];
    for (int f = 0; f < 16; ++f) s += h2[f] * Wf3[f];
    out[b] = s;
  }
}

// ---------------- host ----------------

extern "C" void kernel_launch(void* const* d_in, const int* in_sizes, int n_in,
                              void* d_out, int out_size, void* d_ws, size_t ws_size,
                              hipStream_t stream) {
  const float* x_in = (const float*)d_in[0];
  const int* ei = (const int*)d_in[1];      // int32 per harness contract
  const float* W1l = (const float*)d_in[2];
  const float* b1  = (const float*)d_in[3];
  const float* W1r = (const float*)d_in[4];
  const float* W2l = (const float*)d_in[5];
  const float* b2  = (const float*)d_in[6];
  const float* W2r = (const float*)d_in[7];
  const float* W3l = (const float*)d_in[8];
  const float* b3  = (const float*)d_in[9];
  const float* W3r = (const float*)d_in[10];
  const float* W4l = (const float*)d_in[11];
  const float* b4  = (const float*)d_in[12];
  const float* W4r = (const float*)d_in[13];
  const float* Wf1 = (const float*)d_in[14];
  const float* bf1 = (const float*)d_in[15];
  const float* Wf2 = (const float*)d_in[16];
  const float* bf2 = (const float*)d_in[17];
  const float* Wf3 = (const float*)d_in[18];
  const float* bf3 = (const float*)d_in[19];
  float* out = (float*)d_out;
  (void)in_sizes; (void)n_in; (void)out_size;

  char* ws = (char*)d_ws;
  size_t off = 0;
  auto alloc = [&](size_t bytes) -> void* {
    void* p = ws + off;
    off = (off + bytes + 255) & ~(size_t)255;
    return p;
  };
  unsigned short* xbf = (unsigned short*)alloc((size_t)NN * 8512 * 2);
  unsigned short* wb1 = (unsigned short*)alloc((size_t)640 * 8512 * 2);
  unsigned short* wb2 = (unsigned short*)alloc((size_t)384 * 320 * 2);
  unsigned short* wb3 = (unsigned short*)alloc((size_t)256 * 192 * 2);
  unsigned short* wb4 = (unsigned short*)alloc((size_t)128 * 128 * 2);
  float* y    = (float*)alloc((size_t)NN * 640 * 4);
  float* z    = (float*)alloc((size_t)NN * 320 * 4);
  // contiguous zero region: deg(16K) + cursor(16K) + bnsum(5120B)
  int* deg    = (int*)alloc(NN * 4);
  int* cursor = (int*)alloc(NN * 4);
  float* bnsum = (float*)alloc(1280 * 4);   // 640+360+180+100 floats
  int* offb   = (int*)alloc(NN * 4);
  int* eix    = (int*)alloc(NE * 4);
  if (ws_size < off) return;
  float* bns1 = bnsum;             // 2*320
  float* bns2 = bnsum + 640;       // 2*180
  float* bns3 = bnsum + 1000;      // 2*90
  float* bns4 = bnsum + 1180;      // 2*50

  hipMemsetAsync(deg, 0, 2 * NN * 4 + 1280 * 4, stream);
  hipMemsetAsync(y, 0, (size_t)NN * 640 * 4, stream);   // K-split atomic epilogue

  setup_all<<<dim3(SETUP_BLK), dim3(256), 0, stream>>>(
      x_in, ei + NE, W1l, W1r, W2l, W2r, W3l, W3r, W4l, W4r,
      xbf, wb1, wb2, wb3, wb4, deg);
  scan_deg<<<dim3(1), dim3(1024), 0, stream>>>(deg, offb);
  scatter_edges<<<dim3(NE / 256), dim3(256), 0, stream>>>(ei, ei + NE, offb, cursor, eix);

  // ---- layer 1: K=8512, N=640, K-split x8 (1280 blocks = 5/CU) ----
  gemm_bt<<<dim3(32, 5, 8), dim3(256), 0, stream>>>(xbf, wb1, y, 640, 8512);
  sage_agg<<<dim3(NN, 5), dim3(64), 0, stream>>>(y, offb, deg, eix, b1, z, 320, 640);
  bn_part<<<dim3(5, 8), dim3(64, 4), 0, stream>>>(z, bns1, 320);
  bn_norm8<<<dim3(NN * 40 / 256), dim3(256), 0, stream>>>(z, bns1, xbf, 320, 320);

  // ---- layer 2: K=320, N=384 ----
  gemm_bt<<<dim3(32, 3, 1), dim3(256), 0, stream>>>(xbf, wb2, y, 384, 320);
  sage_agg<<<dim3(NN, 3), dim3(64), 0, stream>>>(y, offb, deg, eix, b2, z, 180, 384);
  bn_part<<<dim3(3, 8), dim3(64, 4), 0, stream>>>(z, bns2, 180);
  bn_norm8<<<dim3(NN * 24 / 256), dim3(256), 0, stream>>>(z, bns2, xbf, 180, 192);

  // ---- layer 3: K=192, N=256 ----
  gemm_bt<<<dim3(32, 2, 1), dim3(256), 0, stream>>>(xbf, wb3, y, 256, 192);
  sage_agg<<<dim3(NN, 2), dim3(64), 0, stream>>>(y, offb, deg, eix, b3, z, 90, 256);
  bn_part<<<dim3(2, 8), dim3(64, 4), 0, stream>>>(z, bns3, 90);
  bn_norm8<<<dim3(NN * 16 / 256), dim3(256), 0, stream>>>(z, bns3, xbf, 90, 128);

  // ---- layer 4: K=128, N=128 ----
  gemm_bt<<<dim3(32, 1, 1), dim3(256), 0, stream>>>(xbf, wb4, y, 128, 128);
  sage_agg<<<dim3(NN, 1), dim3(64), 0, stream>>>(y, offb, deg, eix, b4, z, 50, 128);
  bn_part<<<dim3(1, 8), dim3(64, 4), 0, stream>>>(z, bns4, 50);

  // ---- pool (BN folded) + FC ----
  pool_fc<<<dim3(16), dim3(64), 0, stream>>>(z, bns4, Wf1, bf1, Wf2, bf2, Wf3, bf3, out);
}

// Round 4
// 516.405 us; speedup vs baseline: 1.1026x; 1.0835x over previous
//
#include <hip/hip_runtime.h>
#include <stdint.h>

#define NN 4096
#define NE 65536
#define LEAKY 0.01f
#define BN_EPS 1e-5f

typedef float f32x4 __attribute__((ext_vector_type(4)));
typedef __bf16 bf16x8 __attribute__((ext_vector_type(8)));
typedef unsigned short u16x8 __attribute__((ext_vector_type(8)));

static __device__ __forceinline__ unsigned short f2bf(float v) {
  unsigned int u = __float_as_uint(v);
  u += 0x7fff + ((u >> 16) & 1);   // RNE; inputs are finite
  return (unsigned short)(u >> 16);
}

typedef __attribute__((address_space(1))) void gvoid;
typedef __attribute__((address_space(3))) void lvoid;

static __device__ __forceinline__ void async16(const void* g, void* l) {
  __builtin_amdgcn_global_load_lds((gvoid*)(uintptr_t)g,
                                   (lvoid*)(uint32_t)(uintptr_t)l, 16, 0, 0);
}

// ======================= fused setup: packs + degree count =================
// bf16 GEMM-input layout: within each 64-col K-group, row r's 16B block b is
// stored at block (b + r) & 7 (LDS de-conflict rotation; GEMM unrotates).

static __device__ __forceinline__ void pack_w_seg(int lblk, const float* __restrict__ Wl,
                                                  const float* __restrict__ Wr,
                                                  unsigned short* __restrict__ dst,
                                                  int Fout, int Fin, int Kp, int Np) {
  int nb = Kp >> 3;
  int idx = lblk * 256 + threadIdx.x;
  if (idx >= Np * nb) return;
  int row = idx / nb, kb = idx - row * nb;
  int g = kb >> 3, b = kb & 7;
  int dkb = (g << 3) | ((b + row) & 7);
  const float* src = nullptr;
  if (row < Fout)          src = Wl + (size_t)row * Fin;
  else if (row < 2 * Fout) src = Wr + (size_t)(row - Fout) * Fin;
  u16x8 st;
#pragma unroll
  for (int o = 0; o < 8; ++o) {
    int k = kb * 8 + o;
    float v = (src && k < Fin) ? src[k] : 0.f;
    st[o] = f2bf(v);
  }
  *(u16x8*)&dst[(size_t)row * Kp + dkb * 8] = st;
}

#define PX_BLK   17024   // 4096*1064/256
#define PW1_BLK   2660   // 640*1064/256
#define PW2_BLK     60   // ceil(384*40/256)
#define PW3_BLK     24   // ceil(256*24/256)
#define PW4_BLK      8   // ceil(128*16/256)
#define CD_BLK     256   // 65536/256
#define SETUP_BLK (PX_BLK + PW1_BLK + PW2_BLK + PW3_BLK + PW4_BLK + CD_BLK)

__global__ __launch_bounds__(256) void setup_all(
    const float* __restrict__ x, const int* __restrict__ dsti,
    const float* __restrict__ W1l, const float* __restrict__ W1r,
    const float* __restrict__ W2l, const float* __restrict__ W2r,
    const float* __restrict__ W3l, const float* __restrict__ W3r,
    const float* __restrict__ W4l, const float* __restrict__ W4r,
    unsigned short* __restrict__ xbf, unsigned short* __restrict__ wb1,
    unsigned short* __restrict__ wb2, unsigned short* __restrict__ wb3,
    unsigned short* __restrict__ wb4, int* __restrict__ deg) {
  int blk = blockIdx.x;
  if (blk < PX_BLK) {
    int idx = blk * 256 + threadIdx.x;
    int row = idx / 1064, kb = idx - row * 1064;
    int g = kb >> 3, b = kb & 7;
    int dkb = (g << 3) | ((b + row) & 7);
    const float* src = x + (size_t)row * 8500 + kb * 8;
    float v[8];
    if (kb < 1062) {
      f32x4 a = *(const f32x4*)src;
      f32x4 c = *(const f32x4*)(src + 4);
#pragma unroll
      for (int o = 0; o < 4; ++o) { v[o] = a[o]; v[o + 4] = c[o]; }
    } else {
#pragma unroll
      for (int o = 0; o < 8; ++o) {
        int k = kb * 8 + o;
        v[o] = (k < 8500) ? x[(size_t)row * 8500 + k] : 0.f;
      }
    }
    u16x8 st;
#pragma unroll
    for (int o = 0; o < 8; ++o) st[o] = f2bf(v[o]);
    *(u16x8*)&xbf[(size_t)row * 8512 + dkb * 8] = st;
  } else if (blk < PX_BLK + PW1_BLK) {
    pack_w_seg(blk - PX_BLK, W1l, W1r, wb1, 320, 8500, 8512, 640);
  } else if (blk < PX_BLK + PW1_BLK + PW2_BLK) {
    pack_w_seg(blk - PX_BLK - PW1_BLK, W2l, W2r, wb2, 180, 320, 320, 384);
  } else if (blk < PX_BLK + PW1_BLK + PW2_BLK + PW3_BLK) {
    pack_w_seg(blk - PX_BLK - PW1_BLK - PW2_BLK, W3l, W3r, wb3, 90, 180, 192, 256);
  } else if (blk < PX_BLK + PW1_BLK + PW2_BLK + PW3_BLK + PW4_BLK) {
    pack_w_seg(blk - PX_BLK - PW1_BLK - PW2_BLK - PW3_BLK, W4l, W4r, wb4, 50, 90, 128, 128);
  } else {
    int e = (blk - (SETUP_BLK - CD_BLK)) * 256 + threadIdx.x;
    atomicAdd(&deg[dsti[e]], 1);
  }
}

// ---------------- CSR scan + scatter ----------------

__global__ __launch_bounds__(1024) void scan_deg(const int* __restrict__ deg,
                                                 int* __restrict__ off) {
  __shared__ int s[NN];
  int t = threadIdx.x;
  for (int i = t; i < NN; i += 1024) s[i] = deg[i];
  __syncthreads();
  for (int step = 1; step < NN; step <<= 1) {
    int v[4];
#pragma unroll
    for (int j = 0; j < 4; ++j) {
      int i = t + j * 1024;
      v[j] = (i >= step) ? s[i - step] : 0;
    }
    __syncthreads();
#pragma unroll
    for (int j = 0; j < 4; ++j) s[t + j * 1024] += v[j];
    __syncthreads();
  }
  for (int i = t; i < NN; i += 1024) off[i] = (i == 0) ? 0 : s[i - 1];
}

__global__ void scatter_edges(const int* __restrict__ src_idx,
                              const int* __restrict__ dst_idx,
                              const int* __restrict__ off, int* __restrict__ cursor,
                              int* __restrict__ eix) {
  int e = blockIdx.x * 256 + threadIdx.x;
  if (e < NE) {
    int d = dst_idx[e];
    int pos = atomicAdd(&cursor[d], 1);
    eix[off[d] + pos] = src_idx[e];
  }
}

// ---------------- bf16 MFMA GEMM: C[M,N] = A[M,K] @ B[N,K]^T ----------------
// 128x128 tile, BK=64, 256 threads.  K-split over gridDim.z writes PARTIALS to
// C + z*M*N (plain stores, no atomics); caller reduces.
__global__ __launch_bounds__(256) void gemm_bt(const unsigned short* __restrict__ A,
                                               const unsigned short* __restrict__ B,
                                               float* __restrict__ C, int N, int K,
                                               int M) {
  __shared__ unsigned short smem[2 * 128 * 64];
  unsigned short* As = smem;
  unsigned short* Bs = smem + 128 * 64;

  const int t = threadIdx.x;
  const int bm = blockIdx.x, bn = blockIdx.y;
  const int lane = t & 63;
  const int wave = t >> 6;
  const int wm = (wave & 1) * 64, wn = (wave >> 1) * 64;
  const int l16 = lane & 15, quad = lane >> 4;

  const int ksteps = K >> 6;
  const int gz = (int)gridDim.z;
  const int per = (ksteps + gz - 1) / gz;
  const int k0 = (int)blockIdx.z * per;
  int k1 = k0 + per; if (k1 > ksteps) k1 = ksteps;

  f32x4 zero = {0.f, 0.f, 0.f, 0.f};
  f32x4 acc[4][4];
#pragma unroll
  for (int i = 0; i < 4; ++i)
#pragma unroll
    for (int j = 0; j < 4; ++j) acc[i][j] = zero;

  const int srow = t >> 3;          // 0..31
  const int scol = (t & 7) * 8;     // bf16 col, 16B chunks
  const unsigned short* Abase = A + (size_t)(bm * 128) * K + scol;
  const unsigned short* Bbase = B + (size_t)(bn * 128) * K + scol;

  for (int kt = k0; kt < k1; ++kt) {
    const unsigned short* Ag = Abase + kt * 64;
    const unsigned short* Bg = Bbase + kt * 64;
#pragma unroll
    for (int p = 0; p < 4; ++p) {
      int row = p * 32 + srow;
      async16(Ag + (size_t)row * K, &As[row * 64 + scol]);
    }
#pragma unroll
    for (int p = 0; p < 4; ++p) {
      int row = p * 32 + srow;
      async16(Bg + (size_t)row * K, &Bs[row * 64 + scol]);
    }
    __syncthreads();
#pragma unroll
    for (int kh = 0; kh < 2; ++kh) {
      const int s8 = ((kh * 4 + quad + l16) & 7) * 8;   // unrotate
      bf16x8 af[4], bfr[4];
#pragma unroll
      for (int i = 0; i < 4; ++i)
        af[i] = *(const bf16x8*)&As[(wm + i * 16 + l16) * 64 + s8];
#pragma unroll
      for (int j = 0; j < 4; ++j)
        bfr[j] = *(const bf16x8*)&Bs[(wn + j * 16 + l16) * 64 + s8];
#pragma unroll
      for (int i = 0; i < 4; ++i)
#pragma unroll
        for (int j = 0; j < 4; ++j)
          acc[i][j] = __builtin_amdgcn_mfma_f32_16x16x32_bf16(af[i], bfr[j], acc[i][j], 0, 0, 0);
    }
    __syncthreads();
  }

  // C/D layout: row = quad*4 + reg, col = lane&15; partial slab per kz
  float* Cb = C + (size_t)blockIdx.z * M * N;
#pragma unroll
  for (int i = 0; i < 4; ++i) {
    int rbase = bm * 128 + wm + i * 16 + quad * 4;
#pragma unroll
    for (int j = 0; j < 4; ++j) {
      int col = bn * 128 + wn + j * 16 + l16;
      float* cp = Cb + (size_t)rbase * N + col;
#pragma unroll
      for (int r = 0; r < 4; ++r) cp[(size_t)r * N] = acc[i][j][r];
    }
  }
}

// sum 4 K-split partials in place (y = partial 0)
__global__ void reduce4(float* __restrict__ y) {
  int idx = blockIdx.x * 256 + threadIdx.x;   // exact grid: NN*640/4/256
  f32x4* p = (f32x4*)y;
  const int S = NN * 640 / 4;
  f32x4 v = p[idx];
  v += p[idx + S];
  v += p[idx + 2 * S];
  v += p[idx + 3 * S];
  p[idx] = v;
}

// ---------------- fused mean-aggregate + root + bias + leaky ----------------
// block (64,4): tx = feature quad, ty = edge stripe; edges staged in LDS.
__global__ __launch_bounds__(256) void sage_agg(
    const float* __restrict__ y, const int* __restrict__ off,
    const int* __restrict__ deg, const int* __restrict__ eix,
    const float* __restrict__ bias, float* __restrict__ z, int F, int ldy) {
  int i = blockIdx.x;
  int tx = threadIdx.x, ty = threadIdx.y;
  int f4 = (blockIdx.y * 64 + tx) * 4;
  __shared__ int se[64];
  __shared__ float red[3][64][4];
  int start = off[i], d = deg[i];
  bool active = (f4 < F);
  f32x4 s = {0.f, 0.f, 0.f, 0.f};
  for (int base = 0; base < d; base += 64) {
    __syncthreads();
    if (ty == 0 && base + tx < d) se[tx] = eix[start + base + tx];
    __syncthreads();
    int end = d - base; if (end > 64) end = 64;
    if (active) {
      for (int e = ty; e < end; e += 4)
        s += *(const f32x4*)&y[(size_t)se[e] * ldy + f4];
    }
  }
  if (ty > 0) *(f32x4*)red[ty - 1][tx] = s;
  __syncthreads();
  if (ty == 0 && active) {
    s += *(const f32x4*)red[0][tx];
    s += *(const f32x4*)red[1][tx];
    s += *(const f32x4*)red[2][tx];
    float inv = 1.f / (float)(d > 1 ? d : 1);
    int cnt = F - f4; if (cnt > 4) cnt = 4;
    const float* yr = &y[(size_t)i * ldy + F + f4];
    float* zo = &z[(size_t)i * F + f4];
    for (int j = 0; j < cnt; ++j) {
      float w = s[j] * inv + yr[j] + bias[f4 + j];
      zo[j] = (w >= 0.f) ? w : LEAKY * w;
    }
  }
}

// ---------------- batchnorm: row-major partial sums + fused finalize --------

__global__ __launch_bounds__(256) void bn_part(const float* __restrict__ z,
                                               float* __restrict__ sums, int F) {
  int tx = threadIdx.x, ty = threadIdx.y;      // block (64,4)
  int f = blockIdx.x * 64 + tx;
  float s = 0.f, s2 = 0.f;
  if (f < F) {
    int r0 = blockIdx.y * 512 + ty * 128;
    for (int j = 0; j < 128; ++j) {
      float v = z[(size_t)(r0 + j) * F + f];
      s += v; s2 += v * v;
    }
  }
  __shared__ float ls[4][64], ls2[4][64];
  ls[ty][tx] = s; ls2[ty][tx] = s2;
  __syncthreads();
  if (ty == 0 && f < F) {
    float S  = ls[0][tx] + ls[1][tx] + ls[2][tx] + ls[3][tx];
    float S2 = ls2[0][tx] + ls2[1][tx] + ls2[2][tx] + ls2[3][tx];
    atomicAdd(&sums[f], S);
    atomicAdd(&sums[F + f], S2);
  }
}

// normalize -> next layer's rotated bf16 input (finalizes BN from sums)
__global__ void bn_norm8(const float* __restrict__ z, const float* __restrict__ sums,
                         unsigned short* __restrict__ xout, int F, int Kp) {
  int nb = Kp >> 3;
  int idx = blockIdx.x * 256 + threadIdx.x;    // exact grid
  int row = idx / nb, kb = idx - row * nb;
  int g = kb >> 3, b = kb & 7;
  int dkb = (g << 3) | ((b + row) & 7);
  u16x8 st;
#pragma unroll
  for (int o = 0; o < 8; ++o) {
    int k = kb * 8 + o;
    float v = 0.f;
    if (k < F) {
      float m  = sums[k] * (1.f / NN);
      float var = sums[F + k] * (1.f / NN) - m * m;
      float rs = rsqrtf(var + BN_EPS);
      v = (z[(size_t)row * F + k] - m) * rs;
    }
    st[o] = f2bf(v);
  }
  *(u16x8*)&xout[(size_t)row * Kp + dkb * 8] = st;
}

// ---------------- pool (BN folded in) + 3 FC layers ----------------
__global__ void pool_fc(const float* __restrict__ z,  // [4096, 50] pre-BN
                        const float* __restrict__ sums,
                        const float* __restrict__ Wf1, const float* __restrict__ bf1,
                        const float* __restrict__ Wf2, const float* __restrict__ bf2,
                        const float* __restrict__ Wf3, const float* __restrict__ bf3,
                        float* __restrict__ out) {
  __shared__ float pool[50];
  __shared__ float h1[32], h2[16];
  int b = blockIdx.x, t = threadIdx.x;  // 64 threads
  if (t < 50) {
    float s = 0.f;
    for (int r = 0; r < 256; ++r) s += z[(size_t)(b * 256 + r) * 50 + t];
    float m  = sums[t] * (1.f / NN);
    float var = sums[50 + t] * (1.f / NN) - m * m;
    float rs = rsqrtf(var + BN_EPS);
    pool[t] = (s - 256.f * m) * rs;   // sum of normalized = (sum - n*m)*rs
  }
  __syncthreads();
  if (t < 32) {
    float s = bf1[t];
    for (int f = 0; f < 50; ++f) s += pool[f] * Wf1[t * 50 + f];
    h1[t] = s;
  }
  __syncthreads();
  if (t < 16) {
    float s = bf2[t];
    for (int f = 0; f < 32; ++f) s += h1[f] * Wf2[t * 32 + f];
    h2[t] = s;
  }
  __syncthreads();
  if (t == 0) {
    float s = bf3[0];
    for (int f = 0; f < 16; ++f) s += h2[f] * Wf3[f];
    out[b] = s;
  }
}

// ---------------- host ----------------

extern "C" void kernel_launch(void* const* d_in, const int* in_sizes, int n_in,
                              void* d_out, int out_size, void* d_ws, size_t ws_size,
                              hipStream_t stream) {
  const float* x_in = (const float*)d_in[0];
  const int* ei = (const int*)d_in[1];      // int32 per harness contract
  const float* W1l = (const float*)d_in[2];
  const float* b1  = (const float*)d_in[3];
  const float* W1r = (const float*)d_in[4];
  const float* W2l = (const float*)d_in[5];
  const float* b2  = (const float*)d_in[6];
  const float* W2r = (const float*)d_in[7];
  const float* W3l = (const float*)d_in[8];
  const float* b3  = (const float*)d_in[9];
  const float* W3r = (const float*)d_in[10];
  const float* W4l = (const float*)d_in[11];
  const float* b4  = (const float*)d_in[12];
  const float* W4r = (const float*)d_in[13];
  const float* Wf1 = (const float*)d_in[14];
  const float* bf1 = (const float*)d_in[15];
  const float* Wf2 = (const float*)d_in[16];
  const float* bf2 = (const float*)d_in[17];
  const float* Wf3 = (const float*)d_in[18];
  const float* bf3 = (const float*)d_in[19];
  float* out = (float*)d_out;
  (void)in_sizes; (void)n_in; (void)out_size;

  char* ws = (char*)d_ws;
  size_t off = 0;
  auto alloc = [&](size_t bytes) -> void* {
    void* p = ws + off;
    off = (off + bytes + 255) & ~(size_t)255;
    return p;
  };
  unsigned short* xbf = (unsigned short*)alloc((size_t)NN * 8512 * 2);
  unsigned short* wb1 = (unsigned short*)alloc((size_t)640 * 8512 * 2);
  unsigned short* wb2 = (unsigned short*)alloc((size_t)384 * 320 * 2);
  unsigned short* wb3 = (unsigned short*)alloc((size_t)256 * 192 * 2);
  unsigned short* wb4 = (unsigned short*)alloc((size_t)128 * 128 * 2);
  float* y    = (float*)alloc((size_t)4 * NN * 640 * 4);  // y + 3 extra K-split partials
  float* z    = (float*)alloc((size_t)NN * 320 * 4);
  // contiguous zero region: deg(16K) + cursor(16K) + bnsum(5120B)
  int* deg    = (int*)alloc(NN * 4);
  int* cursor = (int*)alloc(NN * 4);
  float* bnsum = (float*)alloc(1280 * 4);   // 640+360+180+100 floats
  int* offb   = (int*)alloc(NN * 4);
  int* eix    = (int*)alloc(NE * 4);
  if (ws_size < off) return;
  float* bns1 = bnsum;             // 2*320
  float* bns2 = bnsum + 640;       // 2*180
  float* bns3 = bnsum + 1000;      // 2*90
  float* bns4 = bnsum + 1180;      // 2*50

  hipMemsetAsync(deg, 0, 2 * NN * 4 + 1280 * 4, stream);

  setup_all<<<dim3(SETUP_BLK), dim3(256), 0, stream>>>(
      x_in, ei + NE, W1l, W1r, W2l, W2r, W3l, W3r, W4l, W4r,
      xbf, wb1, wb2, wb3, wb4, deg);
  scan_deg<<<dim3(1), dim3(1024), 0, stream>>>(deg, offb);
  scatter_edges<<<dim3(NE / 256), dim3(256), 0, stream>>>(ei, ei + NE, offb, cursor, eix);

  // ---- layer 1: K=8512, N=640, K-split x4 into partials + reduce ----
  gemm_bt<<<dim3(32, 5, 4), dim3(256), 0, stream>>>(xbf, wb1, y, 640, 8512, NN);
  reduce4<<<dim3(NN * 640 / 4 / 256), dim3(256), 0, stream>>>(y);
  sage_agg<<<dim3(NN, 2), dim3(64, 4), 0, stream>>>(y, offb, deg, eix, b1, z, 320, 640);
  bn_part<<<dim3(5, 8), dim3(64, 4), 0, stream>>>(z, bns1, 320);
  bn_norm8<<<dim3(NN * 40 / 256), dim3(256), 0, stream>>>(z, bns1, xbf, 320, 320);

  // ---- layer 2: K=320, N=384 ----
  gemm_bt<<<dim3(32, 3, 1), dim3(256), 0, stream>>>(xbf, wb2, y, 384, 320, NN);
  sage_agg<<<dim3(NN, 1), dim3(64, 4), 0, stream>>>(y, offb, deg, eix, b2, z, 180, 384);
  bn_part<<<dim3(3, 8), dim3(64, 4), 0, stream>>>(z, bns2, 180);
  bn_norm8<<<dim3(NN * 24 / 256), dim3(256), 0, stream>>>(z, bns2, xbf, 180, 192);

  // ---- layer 3: K=192, N=256 ----
  gemm_bt<<<dim3(32, 2, 1), dim3(256), 0, stream>>>(xbf, wb3, y, 256, 192, NN);
  sage_agg<<<dim3(NN, 1), dim3(64, 4), 0, stream>>>(y, offb, deg, eix, b3, z, 90, 256);
  bn_part<<<dim3(2, 8), dim3(64, 4), 0, stream>>>(z, bns3, 90);
  bn_norm8<<<dim3(NN * 16 / 256), dim3(256), 0, stream>>>(z, bns3, xbf, 90, 128);

  // ---- layer 4: K=128, N=128 ----
  gemm_bt<<<dim3(32, 1, 1), dim3(256), 0, stream>>>(xbf, wb4, y, 128, 128, NN);
  sage_agg<<<dim3(NN, 1), dim3(64, 4), 0, stream>>>(y, offb, deg, eix, b4, z, 50, 128);
  bn_part<<<dim3(1, 8), dim3(64, 4), 0, stream>>>(z, bns4, 50);

  // ---- pool (BN folded) + FC ----
  pool_fc<<<dim3(16), dim3(64), 0, stream>>>(z, bns4, Wf1, bf1, Wf2, bf2, Wf3, bf3, out);
}